// Round 14
// baseline (6826.026 us; speedup 1.0000x reference)
//
#include <hip/hip_runtime.h>
#include <cstdint>
#include <cstddef>

#define T_STEPS 100
#define IN_DIM  140
#define HDIM    256
#define BTOT    4096
#define NBLK    256           // 16 bg x 16 ns, 1 block/CU (persistent)
#define NTHR    512           // 8 waves

typedef _Float16 f16;
typedef _Float16 f16x8 __attribute__((ext_vector_type(8)));
typedef float    f32x4 __attribute__((ext_vector_type(4)));

#define NS0 13
#define NS1 16
#define NSA 8
#define E0 (NS0*64*512)
#define E1 (NS1*64*512)
#define EA (NSA*16*512)
#define F16TOT (E0+E1+EA)     // ~2MB f16
#define EB 2048
#define PREP_TOT (F16TOT+EB)

// d_ws layout (bytes)
#define OFF_WSB  ((size_t)F16TOT*2)
#define OFF_H0   (OFF_WSB + (size_t)EB*4)
#define HBUF_E   ((size_t)2*BTOT*HDIM)          // elems per (double-buffered) h buf
#define OFF_H1   (OFF_H0 + HBUF_E*2)
#define OFF_AP   (OFF_H1 + HBUF_E*2)            // advpart: BTOT x 16 f32
#define OFF_SY   (OFF_AP + (size_t)BTOT*16*4)   // 2 x u32 sync

__device__ __forceinline__ float sigmoidf_(float x) {
    return 1.0f / (1.0f + __expf(-x));
}
__device__ __forceinline__ float tanhf_(float x) {
    return 1.0f - 2.0f / (__expf(2.0f * x) + 1.0f);
}

// Pack weights into MFMA B-fragment order (fp16) + folded fp32 biases.
// Frag (ks, nt): lane l, elem e -> B[k = ks*32 + (l>>4)*8 + e][n = nt*16 + (l&15)]
__global__ void prep(const float* __restrict__ Wih0, const float* __restrict__ Whh0,
                     const float* __restrict__ bih0, const float* __restrict__ bhh0,
                     const float* __restrict__ Wih1, const float* __restrict__ Whh1,
                     const float* __restrict__ bih1, const float* __restrict__ bhh1,
                     const float* __restrict__ Wa1,  f16* __restrict__ wsf,
                     float* __restrict__ wsb)
{
    int idx = blockIdx.x * 256 + threadIdx.x;
    if (idx < E0) {
        int e = idx & 7, l = (idx >> 3) & 63, fi = idx >> 9;
        int nt = fi & 63, ks = fi >> 6;
        int k = ks * 32 + ((l >> 4) << 3) + e;
        int n = nt * 16 + (l & 15);
        float v = (k < 160) ? (k < IN_DIM ? Wih0[n * IN_DIM + k] : 0.f)
                            : Whh0[n * HDIM + (k - 160)];
        wsf[idx] = (f16)v;
    } else if (idx < E0 + E1) {
        int i2 = idx - E0;
        int e = i2 & 7, l = (i2 >> 3) & 63, fi = i2 >> 9;
        int nt = fi & 63, ks = fi >> 6;
        int k = ks * 32 + ((l >> 4) << 3) + e;
        int n = nt * 16 + (l & 15);
        float v = (k < HDIM) ? Wih1[n * HDIM + k] : Whh1[n * HDIM + (k - HDIM)];
        wsf[idx] = (f16)v;
    } else if (idx < F16TOT) {
        int i3 = idx - (E0 + E1);
        int e = i3 & 7, l = (i3 >> 3) & 63, fi = i3 >> 9;
        int nt = fi & 15, ks = fi >> 4;
        int k = ks * 32 + ((l >> 4) << 3) + e;
        int j = nt * 16 + (l & 15);
        wsf[idx] = (f16)Wa1[j * HDIM + k];
    } else if (idx < PREP_TOT) {
        int i4 = idx - F16TOT;
        if (i4 < 1024) wsb[i4] = bih0[i4] + bhh0[i4];
        else           wsb[i4] = bih1[i4 - 1024] + bhh1[i4 - 1024];
    }
}

// zero h buffers + sync words each launch (determinism: no leftover state)
__global__ void zero_ws(f16* __restrict__ h0, f16* __restrict__ h1,
                        unsigned* __restrict__ sy)
{
    size_t i = ((size_t)blockIdx.x * 256 + threadIdx.x) * 8;
    if (i < HBUF_E) {
        *(f16x8*)(h0 + i) = (f16x8)(f16)0.f;
        *(f16x8*)(h1 + i) = (f16x8)(f16)0.f;
    }
    if (blockIdx.x == 0 && threadIdx.x == 0) { sy[0] = 0u; sy[1] = 0u; }
}

#define GLOAD_LDS(gsrc, ldst)                                              \
    __builtin_amdgcn_global_load_lds(                                      \
        (const __attribute__((address_space(1))) void*)(gsrc),             \
        (__attribute__((address_space(3))) void*)(ldst), 16, 0, 0)

#define MFMA16(A, B, C) __builtin_amdgcn_mfma_f32_16x16x32_f16((A), (B), (C), 0, 0, 0)

__device__ __forceinline__ void grid_sync(unsigned* cnt, unsigned* flag, unsigned& gen)
{
    __syncthreads();                       // drains this block's vmem (stores retired)
    if (threadIdx.x == 0) {
        gen++;
        __threadfence();                   // agent fence: flush writes to coherent point
        unsigned prev = __hip_atomic_fetch_add(cnt, 1u, __ATOMIC_ACQ_REL,
                                               __HIP_MEMORY_SCOPE_AGENT);
        if (prev == (unsigned)(NBLK - 1)) {
            __hip_atomic_store(cnt, 0u, __ATOMIC_RELAXED, __HIP_MEMORY_SCOPE_AGENT);
            __hip_atomic_store(flag, gen, __ATOMIC_RELEASE, __HIP_MEMORY_SCOPE_AGENT);
        } else {
            while (__hip_atomic_load(flag, __ATOMIC_ACQUIRE,
                                     __HIP_MEMORY_SCOPE_AGENT) < gen) {
                __builtin_amdgcn_s_sleep(2);
            }
        }
    }
    __syncthreads();                       // broadcast release/acquire to all waves
}

// Persistent kernel: weights LDS-resident for all T steps; activations stream.
__global__ __launch_bounds__(NTHR)
void lstm_pers(const float* __restrict__ x, const f16* __restrict__ wsf,
               const float* __restrict__ wsb, const float* __restrict__ Wa2,
               const float* __restrict__ ba1, const float* __restrict__ ba2,
               float* __restrict__ out, f16* __restrict__ h0b, f16* __restrict__ h1b,
               float* __restrict__ ap, unsigned* __restrict__ sy)
{
    __shared__ __align__(16) f16 W0L[52 * 512];   // 52KB: gates0 slice (13ks x 4g)
    __shared__ __align__(16) f16 W1L[64 * 512];   // 64KB: gates1 slice (16ks x 4g)
    __shared__ __align__(16) f16 WAL[8 * 512];    // 8KB : adv slice (8ks x 1)

    const int tid = threadIdx.x;
    const int l   = tid & 63;
    const int w   = tid >> 6;          // wave 0..7
    const int lm  = l & 15;            // A-row / C-col lane coord
    const int lk8 = (l >> 4) << 3;     // k element offset within slice
    const int m0  = (l >> 4) << 2;     // C rows m0..m0+3
    const int bg  = blockIdx.x >> 4;   // batch group (256 rows)
    const int ns  = blockIdx.x & 15;   // unit slice (16 units)
    const int R0  = bg * 256;
    const int u   = ns * 16 + lm;      // owned hidden unit of this lane

    const int grow0 = R0 + (2 * w) * 16 + lm;   // A-frag rows (m-tiles 2w, 2w+1)
    const int grow1 = grow0 + 16;

    // ---- load resident weight slices into LDS (once) ----
    for (int fidx = w; fidx < 124; fidx += 8) {
        const f16* src; f16* dst;
        if (fidx < 52)       { int ks = fidx >> 2, g = fidx & 3;
            src = wsf + ((size_t)(ks * 64 + g * 16 + ns)) * 512; dst = W0L + (size_t)fidx * 512; }
        else if (fidx < 116) { int f2 = fidx - 52; int ks = f2 >> 2, g = f2 & 3;
            src = wsf + E0 + ((size_t)(ks * 64 + g * 16 + ns)) * 512; dst = W1L + (size_t)f2 * 512; }
        else                 { int f3 = fidx - 116;
            src = wsf + E0 + E1 + ((size_t)(f3 * 16 + ns)) * 512; dst = WAL + (size_t)f3 * 512; }
        GLOAD_LDS(src + (size_t)l * 8, dst);
    }

    float b0v[4], b1v[4];
    #pragma unroll
    for (int g = 0; g < 4; g++) {
        b0v[g] = wsb[g * 256 + u];
        b1v[g] = wsb[1024 + g * 256 + u];
    }
    const float bAv  = ba1[u];
    const float wa2v = Wa2[u];
    const float ba2v = ba2[0];

    float c0s[2][4], c1s[2][4];
    #pragma unroll
    for (int mt = 0; mt < 2; mt++)
        #pragma unroll
        for (int r = 0; r < 4; r++) { c0s[mt][r] = 0.f; c1s[mt][r] = 0.f; }

    unsigned gen = 0;
    unsigned* cnt  = sy;
    unsigned* flag = sy + 1;

    asm volatile("s_waitcnt vmcnt(0)" ::: "memory");
    __syncthreads();   // weight slices resident

#define LDA(A0, A1, SRC, KOFF) do {                                          \
        A0 = *(const f16x8*)((SRC) + (size_t)grow0 * HDIM + (KOFF) + lk8);   \
        A1 = *(const f16x8*)((SRC) + (size_t)grow1 * HDIM + (KOFF) + lk8);   \
    } while (0)

#define MFMA_B(WL, KS, A0, A1) do {                                          \
        _Pragma("unroll")                                                    \
        for (int g = 0; g < 4; g++) {                                        \
            f16x8 bf = *(const f16x8*)(&(WL)[((KS) * 4 + g) * 512 + l * 8]); \
            acc[0][g] = MFMA16(A0, bf, acc[0][g]);                           \
            acc[1][g] = MFMA16(A1, bf, acc[1][g]);                           \
        }                                                                    \
    } while (0)

    #pragma unroll 1
    for (int t = 0; t < T_STEPS; t++) {
        const int p = t & 1;
        const f16* h0o = h0b + (size_t)(1 - p) * BTOT * HDIM;  // h0(t-1)
        f16*       h0w = h0b + (size_t)p       * BTOT * HDIM;  // h0(t)
        const f16* h1o = h1b + (size_t)(1 - p) * BTOT * HDIM;  // h1(t-1)
        f16*       h1w = h1b + (size_t)p       * BTOT * HDIM;  // h1(t)

        // ================= gates0: K = x(0..159) | h0(160..415) =================
        f32x4 acc[2][4];
        #pragma unroll
        for (int g = 0; g < 4; g++) {
            float b = b0v[g];
            acc[0][g] = (f32x4){b, b, b, b};
            acc[1][g] = (f32x4){b, b, b, b};
        }
        // x slices ks 0..4 (fp32 -> f16 inline)
        {
            const float* xp0 = x + (size_t)grow0 * (T_STEPS * IN_DIM) + (size_t)t * IN_DIM;
            const float* xp1 = x + (size_t)grow1 * (T_STEPS * IN_DIM) + (size_t)t * IN_DIM;
            #pragma unroll
            for (int ks = 0; ks < 4; ks++) {
                const float* q0 = xp0 + ks * 32 + lk8;
                const float* q1 = xp1 + ks * 32 + lk8;
                float4 a0 = *(const float4*)q0, a1 = *(const float4*)(q0 + 4);
                float4 b0 = *(const float4*)q1, b1 = *(const float4*)(q1 + 4);
                f16x8 xa0, xa1;
                xa0[0]=(f16)a0.x; xa0[1]=(f16)a0.y; xa0[2]=(f16)a0.z; xa0[3]=(f16)a0.w;
                xa0[4]=(f16)a1.x; xa0[5]=(f16)a1.y; xa0[6]=(f16)a1.z; xa0[7]=(f16)a1.w;
                xa1[0]=(f16)b0.x; xa1[1]=(f16)b0.y; xa1[2]=(f16)b0.z; xa1[3]=(f16)b0.w;
                xa1[4]=(f16)b1.x; xa1[5]=(f16)b1.y; xa1[6]=(f16)b1.z; xa1[7]=(f16)b1.w;
                MFMA_B(W0L, ks, xa0, xa1);
            }
            { // ks = 4: k in [128,160), guard k < 140
                f16x8 xa0, xa1;
                #pragma unroll
                for (int e = 0; e < 8; e++) {
                    int k = 128 + lk8 + e;
                    xa0[e] = (k < IN_DIM) ? (f16)xp0[k] : (f16)0.f;
                    xa1[e] = (k < IN_DIM) ? (f16)xp1[k] : (f16)0.f;
                }
                MFMA_B(W0L, 4, xa0, xa1);
            }
        }
        // h0 slices ks 5..12 (2-ahead reg ping-pong, A direct from global)
        {
            f16x8 aE0, aE1, aO0, aO1;
            LDA(aE0, aE1, h0o, 0);
            LDA(aO0, aO1, h0o, 32);
            #pragma unroll
            for (int j = 0; j < 3; j++) {
                MFMA_B(W0L, 5 + 2 * j, aE0, aE1);  LDA(aE0, aE1, h0o, (2 * j + 2) * 32);
                MFMA_B(W0L, 6 + 2 * j, aO0, aO1);  LDA(aO0, aO1, h0o, (2 * j + 3) * 32);
            }
            MFMA_B(W0L, 11, aE0, aE1);
            MFMA_B(W0L, 12, aO0, aO1);
        }
        // epilogue: c0, h0 -> global (own 16-unit slice)
        {
            #pragma unroll
            for (int mt = 0; mt < 2; mt++)
                #pragma unroll
                for (int r = 0; r < 4; r++) {
                    float ig = sigmoidf_(acc[mt][0][r]);
                    float fg = sigmoidf_(acc[mt][1][r]);
                    float gv = tanhf_   (acc[mt][2][r]);
                    float og = sigmoidf_(acc[mt][3][r]);
                    float c  = fmaf(fg, c0s[mt][r], ig * gv);
                    c0s[mt][r] = c;
                    int srow = R0 + (2 * w + mt) * 16 + m0 + r;
                    h0w[(size_t)srow * HDIM + u] = (f16)(og * tanhf_(c));
                }
        }

        grid_sync(cnt, flag, gen);     // SYNC1: h0(t) visible everywhere

        // deferred output for step t-1 (advpart(t-1) visible since before SYNC1)
        if (t > 0 && tid < 256) {
            int row = R0 + ns * 16 + (tid >> 4);
            float v = ap[(size_t)row * 16 + (tid & 15)];
            #pragma unroll
            for (int m = 1; m < 16; m <<= 1) v += __shfl_xor(v, m, 64);
            if ((tid & 15) == 0) out[(size_t)(t - 1) * BTOT + row] = v + ba2v;
        }

        // ================= gates1: K = h0(t) | h1(t-1) =================
        #pragma unroll
        for (int g = 0; g < 4; g++) {
            float b = b1v[g];
            acc[0][g] = (f32x4){b, b, b, b};
            acc[1][g] = (f32x4){b, b, b, b};
        }
        {
            f16x8 aE0, aE1, aO0, aO1;
            LDA(aE0, aE1, h0w, 0);
            LDA(aO0, aO1, h0w, 32);
            #pragma unroll
            for (int j = 0; j < 3; j++) {
                MFMA_B(W1L, 2 * j,     aE0, aE1);  LDA(aE0, aE1, h0w, (2 * j + 2) * 32);
                MFMA_B(W1L, 2 * j + 1, aO0, aO1);  LDA(aO0, aO1, h0w, (2 * j + 3) * 32);
            }
            MFMA_B(W1L, 6, aE0, aE1);  LDA(aE0, aE1, h1o, 0);
            MFMA_B(W1L, 7, aO0, aO1);  LDA(aO0, aO1, h1o, 32);
            #pragma unroll
            for (int j = 0; j < 3; j++) {
                MFMA_B(W1L, 8 + 2 * j, aE0, aE1);  LDA(aE0, aE1, h1o, (2 * j + 2) * 32);
                MFMA_B(W1L, 9 + 2 * j, aO0, aO1);  LDA(aO0, aO1, h1o, (2 * j + 3) * 32);
            }
            MFMA_B(W1L, 14, aE0, aE1);
            MFMA_B(W1L, 15, aO0, aO1);
        }
        // epilogue: c1, h1 -> global
        {
            #pragma unroll
            for (int mt = 0; mt < 2; mt++)
                #pragma unroll
                for (int r = 0; r < 4; r++) {
                    float ig = sigmoidf_(acc[mt][0][r]);
                    float fg = sigmoidf_(acc[mt][1][r]);
                    float gv = tanhf_   (acc[mt][2][r]);
                    float og = sigmoidf_(acc[mt][3][r]);
                    float c  = fmaf(fg, c1s[mt][r], ig * gv);
                    c1s[mt][r] = c;
                    int srow = R0 + (2 * w + mt) * 16 + m0 + r;
                    h1w[(size_t)srow * HDIM + u] = (f16)(og * tanhf_(c));
                }
        }

        grid_sync(cnt, flag, gen);     // SYNC2: h1(t) visible everywhere

        // ================= adv partial: K = h1(t), N = own 16 units =================
        {
            f32x4 accA0 = (f32x4){bAv, bAv, bAv, bAv};
            f32x4 accA1 = accA0;
            f16x8 aE0, aE1, aO0, aO1;
            LDA(aE0, aE1, h1w, 0);
            LDA(aO0, aO1, h1w, 32);
            #pragma unroll
            for (int j = 0; j < 3; j++) {
                { f16x8 bf = *(const f16x8*)(&WAL[(2 * j) * 512 + l * 8]);
                  accA0 = MFMA16(aE0, bf, accA0); accA1 = MFMA16(aE1, bf, accA1); }
                LDA(aE0, aE1, h1w, (2 * j + 2) * 32);
                { f16x8 bf = *(const f16x8*)(&WAL[(2 * j + 1) * 512 + l * 8]);
                  accA0 = MFMA16(aO0, bf, accA0); accA1 = MFMA16(aO1, bf, accA1); }
                LDA(aO0, aO1, h1w, (2 * j + 3) * 32);
            }
            { f16x8 bf = *(const f16x8*)(&WAL[6 * 512 + l * 8]);
              accA0 = MFMA16(aE0, bf, accA0); accA1 = MFMA16(aE1, bf, accA1); }
            { f16x8 bf = *(const f16x8*)(&WAL[7 * 512 + l * 8]);
              accA0 = MFMA16(aO0, bf, accA0); accA1 = MFMA16(aO1, bf, accA1); }

            float s[2][4];
            #pragma unroll
            for (int r = 0; r < 4; r++) {
                s[0][r] = fmaxf(accA0[r], 0.f) * wa2v;
                s[1][r] = fmaxf(accA1[r], 0.f) * wa2v;
            }
            #pragma unroll
            for (int m = 1; m < 16; m <<= 1)
                #pragma unroll
                for (int mt = 0; mt < 2; mt++)
                    #pragma unroll
                    for (int r = 0; r < 4; r++)
                        s[mt][r] += __shfl_xor(s[mt][r], m, 64);
            if (lm == 0) {
                #pragma unroll
                for (int mt = 0; mt < 2; mt++)
                    #pragma unroll
                    for (int r = 0; r < 4; r++) {
                        int srow = R0 + (2 * w + mt) * 16 + m0 + r;
                        ap[(size_t)srow * 16 + ns] = s[mt][r];
                    }
            }
        }
        // advpart(t) written before SYNC1(t+1); next gates0 reads h0w (visible).
    }

    grid_sync(cnt, flag, gen);         // final: advpart(T-1) visible
    if (tid < 256) {
        int row = R0 + ns * 16 + (tid >> 4);
        float v = ap[(size_t)row * 16 + (tid & 15)];
        #pragma unroll
        for (int m = 1; m < 16; m <<= 1) v += __shfl_xor(v, m, 64);
        if ((tid & 15) == 0) out[(size_t)(T_STEPS - 1) * BTOT + row] = v + ba2v;
    }
#undef LDA
#undef MFMA_B
}

extern "C" void kernel_launch(void* const* d_in, const int* in_sizes, int n_in,
                              void* d_out, int out_size, void* d_ws, size_t ws_size,
                              hipStream_t stream)
{
    const float* x    = (const float*)d_in[0];
    const float* Wih0 = (const float*)d_in[1];
    const float* Whh0 = (const float*)d_in[2];
    const float* bih0 = (const float*)d_in[3];
    const float* bhh0 = (const float*)d_in[4];
    const float* Wih1 = (const float*)d_in[5];
    const float* Whh1 = (const float*)d_in[6];
    const float* bih1 = (const float*)d_in[7];
    const float* bhh1 = (const float*)d_in[8];
    const float* Wa1  = (const float*)d_in[9];
    const float* ba1  = (const float*)d_in[10];
    const float* Wa2  = (const float*)d_in[11];
    const float* ba2  = (const float*)d_in[12];

    char* ws = (char*)d_ws;
    f16*      wsf = (f16*)ws;
    float*    wsb = (float*)(ws + OFF_WSB);
    f16*      h0b = (f16*)(ws + OFF_H0);
    f16*      h1b = (f16*)(ws + OFF_H1);
    float*    ap  = (float*)(ws + OFF_AP);
    unsigned* sy  = (unsigned*)(ws + OFF_SY);
    float*    out = (float*)d_out;

    hipLaunchKernelGGL(prep, dim3(PREP_TOT / 256), dim3(256), 0, stream,
                       Wih0, Whh0, bih0, bhh0, Wih1, Whh1, bih1, bhh1, Wa1, wsf, wsb);
    hipLaunchKernelGGL(zero_ws, dim3((HBUF_E / 8 + 255) / 256), dim3(256), 0, stream,
                       h0b, h1b, sy);
    hipLaunchKernelGGL(lstm_pers, dim3(NBLK), dim3(NTHR), 0, stream,
                       x, wsf, wsb, Wa2, ba1, ba2, out, h0b, h1b, ap, sy);
}

// Round 15
// 1943.372 us; speedup vs baseline: 3.5125x; 3.5125x over previous
//
#include <hip/hip_runtime.h>
#include <cstdint>
#include <cstddef>

#define T_STEPS 100
#define IN_DIM  140
#define HDIM    256
#define BTOT    4096
#define MROWS   16
#define NBLK    (BTOT/MROWS)  // 256 blocks
#define NTHR    1024          // 16 waves, 4/SIMD

typedef _Float16 f16;
typedef _Float16 f16x8 __attribute__((ext_vector_type(8)));
typedef float    f32x4 __attribute__((ext_vector_type(4)));

#define NS0 13
#define NS1 16
#define NSA 8
#define E0 (NS0*64*512)
#define E1 (NS1*64*512)
#define EA (NSA*16*512)
#define F16TOT (E0+E1+EA)     // ~2MB f16
#define EB 2048
#define PREP_TOT (F16TOT+EB)
#define SL (64*512)           // f16 per k-slice (gates sections)

// LDS activation tile: cols 0-159 x(padded), 160-415 h0, 416-671 h1, 672-679 pad
#define ACOLS 680
#define H0COL 160
#define H1COL 416

__device__ __forceinline__ float sigmoidf_(float x) {
    return 1.0f / (1.0f + __expf(-x));
}
__device__ __forceinline__ float tanhf_(float x) {
    return 1.0f - 2.0f / (__expf(2.0f * x) + 1.0f);
}

// Pack weights into MFMA B-fragment order (fp16) + folded fp32 biases.
// Frag (ks, nt): lane l, elem e -> B[k = ks*32 + (l>>4)*8 + e][n = nt*16 + (l&15)]
__global__ void prep(const float* __restrict__ Wih0, const float* __restrict__ Whh0,
                     const float* __restrict__ bih0, const float* __restrict__ bhh0,
                     const float* __restrict__ Wih1, const float* __restrict__ Whh1,
                     const float* __restrict__ bih1, const float* __restrict__ bhh1,
                     const float* __restrict__ Wa1,  f16* __restrict__ wsf,
                     float* __restrict__ wsb)
{
    int idx = blockIdx.x * 256 + threadIdx.x;
    if (idx < E0) {
        int e = idx & 7, l = (idx >> 3) & 63, fi = idx >> 9;
        int nt = fi & 63, ks = fi >> 6;
        int k = ks * 32 + ((l >> 4) << 3) + e;
        int n = nt * 16 + (l & 15);
        float v = (k < 160) ? (k < IN_DIM ? Wih0[n * IN_DIM + k] : 0.f)
                            : Whh0[n * HDIM + (k - 160)];
        wsf[idx] = (f16)v;
    } else if (idx < E0 + E1) {
        int i2 = idx - E0;
        int e = i2 & 7, l = (i2 >> 3) & 63, fi = i2 >> 9;
        int nt = fi & 63, ks = fi >> 6;
        int k = ks * 32 + ((l >> 4) << 3) + e;
        int n = nt * 16 + (l & 15);
        float v = (k < HDIM) ? Wih1[n * HDIM + k] : Whh1[n * HDIM + (k - HDIM)];
        wsf[idx] = (f16)v;
    } else if (idx < F16TOT) {
        int i3 = idx - (E0 + E1);
        int e = i3 & 7, l = (i3 >> 3) & 63, fi = i3 >> 9;
        int nt = fi & 15, ks = fi >> 4;
        int k = ks * 32 + ((l >> 4) << 3) + e;
        int j = nt * 16 + (l & 15);
        wsf[idx] = (f16)Wa1[j * HDIM + k];
    } else if (idx < PREP_TOT) {
        int i4 = idx - F16TOT;
        if (i4 < 1024) wsb[i4] = bih0[i4] + bhh0[i4];
        else           wsb[i4] = bih1[i4 - 1024] + bhh1[i4 - 1024];
    }
}

#define GLOAD_LDS(gsrc, ldst)                                              \
    __builtin_amdgcn_global_load_lds(                                      \
        (const __attribute__((address_space(1))) void*)(gsrc),             \
        (__attribute__((address_space(3))) void*)(ldst), 16, 0, 0)

// lgkm-only barrier: does NOT drain vmcnt, so in-flight global loads
// (B-frag register prefetch) cross it. Safe: every cross-wave LDS hazard
// is a ds-op (lgkm-tracked).
#define BAR_LG do { asm volatile("s_waitcnt lgkmcnt(0)" ::: "memory");     \
                    __builtin_amdgcn_sched_barrier(0);                     \
                    __builtin_amdgcn_s_barrier();                          \
                    __builtin_amdgcn_sched_barrier(0); } while (0)

// Lessons encoded (R10-R14):
//  - Keep slice loops as LOOPS; full unroll -> address hoisting -> spill.
//  - Grid-wide h exchange is HBM-priced on MI355X (per-XCD L2 non-coherent);
//    the recurrence must stay inside a block (R14: 4.4GB HBM fetch, 3.7x worse).
//  - 16 waves (4/SIMD): per-wave 4 loads + 4 MFMAs per slice; per-CU weight
//    bytes unchanged; 2x TLP hides L2 latency. VGPR ~100 fits the 128 cap.
__global__ __launch_bounds__(NTHR)
void lstm_mfma(
    const float* __restrict__ x, const f16* __restrict__ wsf,
    const float* __restrict__ wsb, const float* __restrict__ Wa2,
    const float* __restrict__ ba1, const float* __restrict__ ba2,
    float* __restrict__ out)
{
    __shared__ __align__(16) f16 A[MROWS][ACOLS];       // 21760 B
    __shared__ __align__(16) f16 advL[16 * 8 * 512];    // 128 KB: adv weights, LDS-pinned
    __shared__ float red[16][MROWS];                    // 1 KB

    const int tid = threadIdx.x;
    const int l   = tid & 63;
    const int w   = tid >> 6;         // wave 0..15
    const int lm  = l & 15;           // A-row / C-col(n) lane coord
    const int lk  = (l >> 4) << 3;    // k-offset within a 32-slice
    const int m0  = (l >> 4) << 2;    // C rows m0..m0+3
    const int row0 = blockIdx.x * MROWS;

    const f16* W0 = wsf;
    const f16* W1 = wsf + E0;
    const f16* WA = wsf + E0 + E1;

    // zero activation tile
    for (int i = tid; i < MROWS * ACOLS; i += NTHR) ((f16*)A)[i] = (f16)0.f;

    const int u = w * 16 + lm;        // the ONE hidden unit this lane owns
    float b0v[4], b1v[4];
    #pragma unroll
    for (int g = 0; g < 4; g++) {
        b0v[g] = wsb[g * 256 + u];
        b1v[g] = wsb[1024 + g * 256 + u];
    }
    const float bAv  = ba1[u];
    const float wa2v = Wa2[u];
    const float ba2v = ba2[0];

    // stage adv weights into LDS once (wave w's 8 frags: col tile w, ks 0..7)
    #pragma unroll
    for (int ks = 0; ks < NSA; ks++) {
        const f16* src = WA + ((size_t)(ks * 16 + w)) * 512 + l * 8;
        GLOAD_LDS(src, advL + (size_t)(w * 8 + ks) * 512);
    }

    float c0s[4], c1s[4];
    #pragma unroll
    for (int r = 0; r < 4; r++) { c0s[r] = 0.f; c1s[r] = 0.f; }

    // prologue: stage x_0
    for (int i = tid; i < MROWS * IN_DIM; i += NTHR) {
        int b = i / IN_DIM, k = i - b * IN_DIM;
        A[b][k] = (f16)x[(size_t)(row0 + b) * (T_STEPS * IN_DIM) + k];
    }

    // Two B-fragment register sets (32 VGPR total): slice k lives in set k&1.
    // Wave w's 4 frags of slice base: nt = g*16 + w, g = 0..3.
    f16x8 bsE[4], bsO[4];

#define LDSETX(ARR, BASE)                                                  \
    do { _Pragma("unroll")                                                 \
         for (int g = 0; g < 4; g++)                                       \
             ARR[g] = *(const f16x8*)((BASE) +                             \
                        ((size_t)((g << 4) + w) << 9) + l * 8);            \
    } while (0)

#define MFMA_SX(ARR, COL)                                                  \
    do { f16x8 a0 = *(const f16x8*)&A[lm][(COL) + lk];                     \
         _Pragma("unroll")                                                 \
         for (int g = 0; g < 4; g++)                                       \
             acc[g] = __builtin_amdgcn_mfma_f32_16x16x32_f16(              \
                 a0, ARR[g], acc[g], 0, 0, 0);                             \
    } while (0)

    // preload gates0 slices 0,1 (canonical: even->bsE, odd->bsO)
    LDSETX(bsE, W0 + 0 * SL);
    LDSETX(bsO, W0 + 1 * SL);

    __syncthreads();   // full drain (prologue only): A zeroed + x0 + advL resident

    #pragma unroll 1
    for (int t = 0; t < T_STEPS; t++) {
        // ======== gates0: 13 slices, 2-ahead ping-pong ========
        f32x4 acc[4];
        #pragma unroll
        for (int g = 0; g < 4; g++) {
            float b = b0v[g];
            acc[g] = (f32x4){b, b, b, b};
        }
        #pragma unroll 1
        for (int j = 0; j < 5; j++) {          // slices k=2j (E), 2j+1 (O); load k+2
            MFMA_SX(bsE, (2 * j) * 32);     LDSETX(bsE, W0 + (size_t)(2 * j + 2) * SL);
            MFMA_SX(bsO, (2 * j + 1) * 32); LDSETX(bsO, W0 + (size_t)(2 * j + 3) * SL);
        }
        // peeled tail: k=10,11,12 ; tail loads restore canonical parity for gates1
        MFMA_SX(bsE, 10 * 32);  LDSETX(bsE, W0 + 12 * SL);
        MFMA_SX(bsO, 11 * 32);  LDSETX(bsO, W1 + 1 * SL);   // gates1 s1 (odd)
        MFMA_SX(bsE, 12 * 32);  LDSETX(bsE, W1 + 0 * SL);   // gates1 s0 (even)

        // epilogue: c0,h0 (one unit per lane, 4 rows)
        f16 hnew[4];
        #pragma unroll
        for (int r = 0; r < 4; r++) {
            float ig = sigmoidf_(acc[0][r]);
            float fg = sigmoidf_(acc[1][r]);
            float gv = tanhf_   (acc[2][r]);
            float og = sigmoidf_(acc[3][r]);
            float c  = fmaf(fg, c0s[r], ig * gv);
            c0s[r] = c;
            hnew[r] = (f16)(og * tanhf_(c));
        }
        BAR_LG;            // B2: all gates0 A-reads done (8 loads stay in flight)
        #pragma unroll
        for (int r = 0; r < 4; r++)
            A[m0 + r][H0COL + u] = hnew[r];
        BAR_LG;            // B3: h0 visible

        // ======== gates1: 16 slices, 2-ahead ping-pong ========
        #pragma unroll
        for (int g = 0; g < 4; g++) {
            float b = b1v[g];
            acc[g] = (f32x4){b, b, b, b};
        }
        #pragma unroll 1
        for (int j = 0; j < 7; j++) {          // slices k=2j (E), 2j+1 (O); load k+2
            MFMA_SX(bsE, H0COL + (2 * j) * 32);     LDSETX(bsE, W1 + (size_t)(2 * j + 2) * SL);
            MFMA_SX(bsO, H0COL + (2 * j + 1) * 32); LDSETX(bsO, W1 + (size_t)(2 * j + 3) * SL);
        }
        // peeled tail: k=14,15 ; loads fetch next step's gates0 s0,s1 (canonical)
        MFMA_SX(bsE, H0COL + 14 * 32);  LDSETX(bsE, W0 + 0 * SL);
        MFMA_SX(bsO, H0COL + 15 * 32);  LDSETX(bsO, W0 + 1 * SL);

        // epilogue: c1,h1
        #pragma unroll
        for (int r = 0; r < 4; r++) {
            float ig = sigmoidf_(acc[0][r]);
            float fg = sigmoidf_(acc[1][r]);
            float gv = tanhf_   (acc[2][r]);
            float og = sigmoidf_(acc[3][r]);
            float c  = fmaf(fg, c1s[r], ig * gv);
            c1s[r] = c;
            hnew[r] = (f16)(og * tanhf_(c));
        }
        BAR_LG;            // B4: all gates1 A-reads done
        #pragma unroll
        for (int r = 0; r < 4; r++)
            A[m0 + r][H1COL + u] = hnew[r];
        BAR_LG;            // B5: h1 visible

        // ======== adv: weights from LDS (pinned), no VMEM ========
        f32x4 accA = (f32x4){bAv, bAv, bAv, bAv};
        #pragma unroll
        for (int ks = 0; ks < NSA; ks++) {
            f16x8 a0 = *(const f16x8*)&A[lm][H1COL + ks * 32 + lk];
            f16x8 bf = *(const f16x8*)(advL + (size_t)(w * 8 + ks) * 512 + l * 8);
            accA = __builtin_amdgcn_mfma_f32_16x16x32_f16(a0, bf, accA, 0, 0, 0);
        }

        // ---- overlap: stage x_{t+1} into A's x region (dead after gates0) ----
        {
            const int tn = (t + 1 < T_STEPS) ? (t + 1) : t;
            for (int i = tid; i < MROWS * IN_DIM; i += NTHR) {
                int b = i / IN_DIM, k = i - b * IN_DIM;
                A[b][k] = (f16)x[(size_t)(row0 + b) * (T_STEPS * IN_DIM) + (size_t)tn * IN_DIM + k];
            }
        }

        // ---- reduce + output ----
        float s[4];
        #pragma unroll
        for (int r = 0; r < 4; r++)
            s[r] = fmaxf(accA[r], 0.f) * wa2v;
        #pragma unroll
        for (int msk = 1; msk < 16; msk <<= 1)
            #pragma unroll
            for (int r = 0; r < 4; r++)
                s[r] += __shfl_xor(s[r], msk, 64);
        if (lm == 0) {
            #pragma unroll
            for (int r = 0; r < 4; r++) red[w][m0 + r] = s[r];
        }
        BAR_LG;            // B6: red + x_{t+1} visible
        if (tid < MROWS) {
            float o = ba2v;
            #pragma unroll
            for (int w2 = 0; w2 < 16; w2++) o += red[w2][tid];
            out[(size_t)t * BTOT + row0 + tid] = o;
        }
    }
#undef LDSETX
#undef MFMA_SX
}

extern "C" void kernel_launch(void* const* d_in, const int* in_sizes, int n_in,
                              void* d_out, int out_size, void* d_ws, size_t ws_size,
                              hipStream_t stream)
{
    const float* x    = (const float*)d_in[0];
    const float* Wih0 = (const float*)d_in[1];
    const float* Whh0 = (const float*)d_in[2];
    const float* bih0 = (const float*)d_in[3];
    const float* bhh0 = (const float*)d_in[4];
    const float* Wih1 = (const float*)d_in[5];
    const float* Whh1 = (const float*)d_in[6];
    const float* bih1 = (const float*)d_in[7];
    const float* bhh1 = (const float*)d_in[8];
    const float* Wa1  = (const float*)d_in[9];
    const float* ba1  = (const float*)d_in[10];
    const float* Wa2  = (const float*)d_in[11];
    const float* ba2  = (const float*)d_in[12];

    f16*   wsf = (f16*)d_ws;
    float* wsb = (float*)((char*)d_ws + (size_t)F16TOT * sizeof(f16));
    float* out = (float*)d_out;

    hipLaunchKernelGGL(prep, dim3(PREP_TOT / 256), dim3(256), 0, stream,
                       Wih0, Whh0, bih0, bhh0, Wih1, Whh1, bih1, bhh1, Wa1, wsf, wsb);
    hipLaunchKernelGGL(lstm_mfma, dim3(NBLK), dim3(NTHR), 0, stream,
                       x, wsf, wsb, Wa2, ba1, ba2, out);
}